// Round 7
// baseline (3902.485 us; speedup 1.0000x reference)
//
#include <hip/hip_runtime.h>
#include <math.h>

typedef __attribute__((ext_vector_type(4))) float f32x4;
typedef __attribute__((ext_vector_type(4))) int   i32x4;
typedef __attribute__((ext_vector_type(8))) short bfrag8;   // 8 bf16 = 4 VGPRs

// ---- ws layout (bytes) ----
// wre_hi: 5 mats * 1024 * 256 * 2B = 2621440 @ 0
// wre_lo: same                              @ 2621440
// hb    : 4 planes * 3 layers * 256*256 * 2B = 1572864 @ 5242880
// tags  : 4 planes * 3 layers * 16 G * 16 nt * 4B = 12288 @ 6815744
#define WRE_LO_OFF 2621440
#define HB_OFF     5242880
#define TAG_OFF    6815744
#define HSTRIDE    65536          // shorts per (plane,layer) slot

// dynamic LDS: [2 mats][2 planes][64 rows][264 bf16]  = 4*64*264*2 = 135168 B
#define WROW 264
#define SMEM_BYTES (4 * 64 * WROW * 2)

__device__ __forceinline__ unsigned short f2bf(float f){
  union { float f; unsigned u; } x; x.f = f;
  unsigned r = x.u + 0x7FFFu + ((x.u >> 16) & 1u);   // RNE
  return (unsigned short)(r >> 16);
}
__device__ __forceinline__ float bf2f(unsigned short s){
  union { unsigned u; float f; } x; x.u = ((unsigned)s) << 16; return x.f;
}
__device__ __forceinline__ float sigf(float x){
  return 1.0f / (1.0f + __expf(-x));
}
__device__ __forceinline__ float tanh_fast(float x){
  x = fminf(fmaxf(x, -15.0f), 15.0f);
  float e = __expf(2.0f * x);
  return (e - 1.0f) / (e + 1.0f);
}

// ---- LLC-direct (coherence-point) access: sc0 sc1 bypasses L1 and L2.
__device__ __forceinline__ i32x4 llc_load_b128(const void* p){
  i32x4 r;
  asm volatile("global_load_dwordx4 %0, %1, off sc0 sc1"
               : "=v"(r) : "v"(p) : "memory");
  return r;
}
__device__ __forceinline__ void llc_store_b16(void* p, unsigned short v){
  unsigned int vv = v;
  asm volatile("global_store_short %0, %1, off sc0 sc1"
               : : "v"(p), "v"(vv) : "memory");
}
__device__ __forceinline__ void wait_vm0(){
  asm volatile("s_waitcnt vmcnt(0)" ::: "memory");
}

// Reorder the 5 big weight mats into per-(nt)-contiguous rows, split bf16 hi/lo.
__global__ void init_reorder(const float* __restrict__ hh0, const float* __restrict__ ih1,
                             const float* __restrict__ hh1, const float* __restrict__ ih2,
                             const float* __restrict__ hh2,
                             unsigned short* __restrict__ wre_hi,
                             unsigned short* __restrict__ wre_lo){
  int e = blockIdx.x * 256 + threadIdx.x;        // 5*2^18 total
  int mat = e >> 18;
  int d   = (e >> 8) & 1023;
  int k   = e & 255;
  int nt = d >> 6, g = (d >> 4) & 3, n = d & 15;
  int src_row = g*256 + nt*16 + n;
  const float* W = (mat==0) ? hh0 : (mat==1) ? ih1 : (mat==2) ? hh1 : (mat==3) ? ih2 : hh2;
  float v = W[src_row*256 + k];
  unsigned short hi = f2bf(v);
  float lo = v - bf2f(hi);
  wre_hi[e] = hi;
  wre_lo[e] = f2bf(lo);
}

__global__ void init_zero(uint4* __restrict__ p, int n16){
  int i = blockIdx.x * 256 + threadIdx.x;
  if (i < n16) p[i] = make_uint4(0u,0u,0u,0u);
}

// tags[((p*3 + l)*16 + G)*16 + nt] = p   (tagval of ancient epochs; plane 3 = h[-1])
__global__ void init_tags(unsigned int* __restrict__ tags){
  int i = blockIdx.x * 256 + threadIdx.x;   // 3072 total
  if (i < 3072) tags[i] = (unsigned)(i / 768);
}

// Point-to-point epoch-tagged LSTM. 192 blocks = layer(3) x nt(16) x bt(4).
// h planes: 4 epochs (t mod 4) per layer. Producing wave: store h chunk (LLC)
// -> vmcnt(0) -> tag[plane][l][G][nt] = t+4 (relaxed agent). Consumer wave
// polls only the 32 tags it depends on (two 64B lines). WAR: self/peer reads
// proven done via RAW chaining; downstream (l+1) guarded by its tag line >= t
// (loaded at loop top, checked before stores). No __syncthreads in the loop.
__global__ void __launch_bounds__(256, 1) lstm_coop(
    const float* __restrict__ tracks,
    const float* __restrict__ wih0,
    const float* __restrict__ bih0, const float* __restrict__ bhh0,
    const float* __restrict__ bih1, const float* __restrict__ bhh1,
    const float* __restrict__ bih2, const float* __restrict__ bhh2,
    const unsigned short* __restrict__ wre_hi, const unsigned short* __restrict__ wre_lo,
    unsigned short* __restrict__ hb, unsigned int* __restrict__ tags);

template<int L>
__device__ __forceinline__ void layer_loop(
    const float* __restrict__ tracks, const float* __restrict__ wih0,
    const float* __restrict__ bihL, const float* __restrict__ bhhL,
    const unsigned short* smem,
    unsigned short* hb, unsigned int* tags,
    int nt, int bt)
{
  const int tid  = threadIdx.x;
  const int w    = tid >> 6, lane = tid & 63;
  const int m    = lane & 15, q = lane >> 4;
  const int b0   = bt * 64, n0 = nt * 16;
  const int G    = bt * 4 + w;

  float bsum[4], wx0[4], wx1[4];
  #pragma unroll
  for (int g = 0; g < 4; ++g){
    int row = g*256 + n0 + m;
    bsum[g] = bihL[row] + bhhL[row];
    if constexpr (L == 0){ wx0[g] = wih0[row*2 + 0]; wx1[g] = wih0[row*2 + 1]; }
  }
  float cst[4] = {0.f, 0.f, 0.f, 0.f};
  const int arow = b0 + 16*w + m;
  const int woff = m*WROW + q*8;
  constexpr int RS = (L == 0) ? 0 : 2;     // recurrent-mat LDS slot base

  for (int t = 0; t < 512; ++t){
    const int pin  = t & 3;                // plane of h_{L-1}[t] and of our output
    const int prec = (t + 3) & 3;          // plane of h_L[t-1]
    const unsigned expi = (unsigned)(t + 4);
    const unsigned expr = (unsigned)(t + 3);

    // ---- early downstream-WAR guard load (checked later, before stores) ----
    unsigned gv = 0u;
    unsigned int* gl = nullptr;
    if constexpr (L < 2){
      gl = tags + ((pin*3 + (L+1))*16 + G)*16;
      if (lane < 16)
        gv = __hip_atomic_load(gl + lane, __ATOMIC_RELAXED, __HIP_MEMORY_SCOPE_AGENT);
    }

    // ---- x prefetch (layer 0 only) ----
    float xv0[4], xv1[4];
    if constexpr (L == 0){
      #pragma unroll
      for (int r = 0; r < 4; ++r){
        const float* px = tracks + (b0 + 16*w + q*4 + r)*1024 + t*2;
        xv0[r] = px[0]; xv1[r] = px[1];
      }
    }

    // ---- RAW poll: only the tags this wave depends on ----
    unsigned int* rcl = tags + ((prec*3 + L)*16 + G)*16;
    unsigned int* inl = nullptr;
    if constexpr (L >= 1) inl = tags + ((pin*3 + (L-1))*16 + G)*16;
    for (;;){
      bool ok = true;
      if constexpr (L >= 1){
        if (lane < 16)
          ok = __hip_atomic_load(inl + lane, __ATOMIC_RELAXED, __HIP_MEMORY_SCOPE_AGENT) >= expi;
        else if (lane < 32)
          ok = __hip_atomic_load(rcl + (lane - 16), __ATOMIC_RELAXED, __HIP_MEMORY_SCOPE_AGENT) >= expr;
      } else {
        if (lane < 16)
          ok = __hip_atomic_load(rcl + lane, __ATOMIC_RELAXED, __HIP_MEMORY_SCOPE_AGENT) >= expr;
      }
      if (__all((int)ok)) break;
    }

    // ---- A fragments: LLC-direct loads (control-dependent on poll) ----
    i32x4 arr[8], ari[8];
    {
      const unsigned short* pr = hb + (prec*3 + L)*HSTRIDE + arow*256 + q*8;
      #pragma unroll
      for (int ks = 0; ks < 8; ++ks) arr[ks] = llc_load_b128(pr + ks*32);
      if constexpr (L >= 1){
        const unsigned short* pi = hb + (pin*3 + (L-1))*HSTRIDE + arow*256 + q*8;
        #pragma unroll
        for (int ks = 0; ks < 8; ++ks) ari[ks] = llc_load_b128(pi + ks*32);
      }
    }
    wait_vm0();

    // ---- MFMA: acc[g] over K=256, W split hi/lo ----
    f32x4 acc[4];
    #pragma unroll
    for (int g = 0; g < 4; ++g) acc[g] = (f32x4){0.f,0.f,0.f,0.f};
    {
      const unsigned short* bh = smem + (RS + 0)*64*WROW + woff;
      const unsigned short* bl = smem + (RS + 1)*64*WROW + woff;
      #pragma unroll
      for (int ks = 0; ks < 8; ++ks){
        bfrag8 a = __builtin_bit_cast(bfrag8, arr[ks]);
        #pragma unroll
        for (int g = 0; g < 4; ++g){
          bfrag8 fh = *(const bfrag8*)(bh + g*16*WROW + ks*32);
          bfrag8 fl = *(const bfrag8*)(bl + g*16*WROW + ks*32);
          acc[g] = __builtin_amdgcn_mfma_f32_16x16x32_bf16(a, fh, acc[g], 0, 0, 0);
          acc[g] = __builtin_amdgcn_mfma_f32_16x16x32_bf16(a, fl, acc[g], 0, 0, 0);
        }
      }
    }
    if constexpr (L >= 1){
      const unsigned short* bh = smem + 0*64*WROW + woff;
      const unsigned short* bl = smem + 1*64*WROW + woff;
      #pragma unroll
      for (int ks = 0; ks < 8; ++ks){
        bfrag8 a = __builtin_bit_cast(bfrag8, ari[ks]);
        #pragma unroll
        for (int g = 0; g < 4; ++g){
          bfrag8 fh = *(const bfrag8*)(bh + g*16*WROW + ks*32);
          bfrag8 fl = *(const bfrag8*)(bl + g*16*WROW + ks*32);
          acc[g] = __builtin_amdgcn_mfma_f32_16x16x32_bf16(a, fh, acc[g], 0, 0, 0);
          acc[g] = __builtin_amdgcn_mfma_f32_16x16x32_bf16(a, fl, acc[g], 0, 0, 0);
        }
      }
    }

    // ---- downstream WAR guard: layer L+1 finished reading h_L[t-4] ----
    if constexpr (L < 2){
      for (;;){
        bool ok = (lane < 16) ? (gv >= (unsigned)t) : true;
        if (__all((int)ok)) break;
        if (lane < 16)
          gv = __hip_atomic_load(gl + lane, __ATOMIC_RELAXED, __HIP_MEMORY_SCOPE_AGENT);
      }
    }

    // ---- cell update (gates in registers; c exact fp32); h stores LLC-direct ----
    unsigned short* hout = hb + (pin*3 + L)*HSTRIDE;
    #pragma unroll
    for (int r = 0; r < 4; ++r){
      float xi = 0.f, xf = 0.f, xg = 0.f, xo = 0.f;
      if constexpr (L == 0){
        xi = xv0[r]*wx0[0] + xv1[r]*wx1[0];
        xf = xv0[r]*wx0[1] + xv1[r]*wx1[1];
        xg = xv0[r]*wx0[2] + xv1[r]*wx1[2];
        xo = xv0[r]*wx0[3] + xv1[r]*wx1[3];
      }
      float gi = acc[0][r] + bsum[0] + xi;
      float gf = acc[1][r] + bsum[1] + xf;
      float gg = acc[2][r] + bsum[2] + xg;
      float go = acc[3][r] + bsum[3] + xo;
      float iv = sigf(gi);
      float fv = sigf(gf);
      float gvv = tanh_fast(gg);
      float ov = sigf(go);
      cst[r] = fv * cst[r] + iv * gvv;
      float hv = ov * tanh_fast(cst[r]);
      llc_store_b16(&hout[(b0 + 16*w + q*4 + r)*256 + n0 + m], f2bf(hv));
    }

    // ---- publish: drain this wave's stores, then post the epoch tag ----
    wait_vm0();
    if (lane == 0)
      __hip_atomic_store(tags + ((pin*3 + L)*16 + G)*16 + nt, (unsigned)(t + 4),
                         __ATOMIC_RELAXED, __HIP_MEMORY_SCOPE_AGENT);
  }
}

__global__ void __launch_bounds__(256, 1) lstm_coop(
    const float* __restrict__ tracks,
    const float* __restrict__ wih0,
    const float* __restrict__ bih0, const float* __restrict__ bhh0,
    const float* __restrict__ bih1, const float* __restrict__ bhh1,
    const float* __restrict__ bih2, const float* __restrict__ bhh2,
    const unsigned short* __restrict__ wre_hi, const unsigned short* __restrict__ wre_lo,
    unsigned short* __restrict__ hb, unsigned int* __restrict__ tags)
{
  extern __shared__ __align__(16) unsigned short smem[];   // [mat][plane][64][WROW]

  const int tid = threadIdx.x;
  const int l   = blockIdx.x >> 6;
  const int r6  = blockIdx.x & 63;
  const int nt  = r6 & 15, bt = r6 >> 4;

  // ---- stage this layer's weight slices into LDS (once) ----
  const int nmats = (l == 0) ? 1 : 2;
  const int gmat0 = (l == 0) ? 0 : (l == 1 ? 1 : 3);
  for (int mi = 0; mi < nmats; ++mi){
    const unsigned short* sh = wre_hi + (gmat0 + mi)*262144 + nt*16384;
    const unsigned short* sl = wre_lo + (gmat0 + mi)*262144 + nt*16384;
    unsigned short* dh = smem + (mi*2 + 0)*64*WROW;
    unsigned short* dl = smem + (mi*2 + 1)*64*WROW;
    for (int c = tid; c < 2048; c += 256){
      int r = c >> 5, off = (c & 31) * 8;
      *(uint4*)(dh + r*WROW + off) = *(const uint4*)(sh + r*256 + off);
      *(uint4*)(dl + r*WROW + off) = *(const uint4*)(sl + r*256 + off);
    }
  }
  __syncthreads();

  if (l == 0)      layer_loop<0>(tracks, wih0, bih0, bhh0, smem, hb, tags, nt, bt);
  else if (l == 1) layer_loop<1>(tracks, wih0, bih1, bhh1, smem, hb, tags, nt, bt);
  else             layer_loop<2>(tracks, wih0, bih2, bhh2, smem, hb, tags, nt, bt);
}

// out[b] = elu(h2_final[b]) @ W_pred^T + b_pred ; h2[511] plane = 511&3 = 3 -> slot 3*3+2 = 11
__global__ void head_kernel(const unsigned short* __restrict__ hb,
                            const float* __restrict__ wpred,
                            const float* __restrict__ bpred,
                            float* __restrict__ out){
  const int b = blockIdx.x;
  const int k = threadIdx.x;
  const int idx = 11*HSTRIDE + b*256 + k;
  float h = bf2f(hb[idx]);
  float e = (h > 0.f) ? h : expm1f(h);
  float v0 = e * wpred[k];
  float v1 = e * wpred[256 + k];
  #pragma unroll
  for (int off = 32; off > 0; off >>= 1){
    v0 += __shfl_down(v0, off, 64);
    v1 += __shfl_down(v1, off, 64);
  }
  __shared__ float r0[4], r1[4];
  int wv = threadIdx.x >> 6, ln = threadIdx.x & 63;
  if (ln == 0){ r0[wv] = v0; r1[wv] = v1; }
  __syncthreads();
  if (threadIdx.x == 0){
    out[b*2 + 0] = r0[0] + r0[1] + r0[2] + r0[3] + bpred[0];
    out[b*2 + 1] = r1[0] + r1[1] + r1[2] + r1[3] + bpred[1];
  }
}

extern "C" void kernel_launch(void* const* d_in, const int* in_sizes, int n_in,
                              void* d_out, int out_size, void* d_ws, size_t ws_size,
                              hipStream_t stream) {
  const float* tracks = (const float*)d_in[0];
  const float* wih0   = (const float*)d_in[1];
  const float* whh0   = (const float*)d_in[2];
  const float* bih0   = (const float*)d_in[3];
  const float* bhh0   = (const float*)d_in[4];
  const float* wih1   = (const float*)d_in[5];
  const float* whh1   = (const float*)d_in[6];
  const float* bih1   = (const float*)d_in[7];
  const float* bhh1   = (const float*)d_in[8];
  const float* wih2   = (const float*)d_in[9];
  const float* whh2   = (const float*)d_in[10];
  const float* bih2   = (const float*)d_in[11];
  const float* bhh2   = (const float*)d_in[12];
  const float* wpred  = (const float*)d_in[13];
  const float* bpred  = (const float*)d_in[14];
  float* out = (float*)d_out;

  char* ws = (char*)d_ws;
  unsigned short* wre_hi = (unsigned short*)(ws);
  unsigned short* wre_lo = (unsigned short*)(ws + WRE_LO_OFF);
  unsigned short* hb     = (unsigned short*)(ws + HB_OFF);
  unsigned int*   tags   = (unsigned int*)(ws + TAG_OFF);

  (void)hipFuncSetAttribute((const void*)lstm_coop,
                            hipFuncAttributeMaxDynamicSharedMemorySize, SMEM_BYTES);

  init_reorder<<<5120, 256, 0, stream>>>(whh0, wih1, whh1, wih2, whh2, wre_hi, wre_lo);
  // zero hb (1572864 B = 98304 uint4)
  init_zero<<<384, 256, 0, stream>>>((uint4*)(ws + HB_OFF), 98304);
  init_tags<<<12, 256, 0, stream>>>(tags);

  void* args[12];
  args[0]  = (void*)&tracks;
  args[1]  = (void*)&wih0;
  args[2]  = (void*)&bih0;
  args[3]  = (void*)&bhh0;
  args[4]  = (void*)&bih1;
  args[5]  = (void*)&bhh1;
  args[6]  = (void*)&bih2;
  args[7]  = (void*)&bhh2;
  args[8]  = (void*)&wre_hi;
  args[9]  = (void*)&wre_lo;
  args[10] = (void*)&hb;
  args[11] = (void*)&tags;
  // cooperative launch kept purely for the all-blocks-co-resident guarantee
  hipLaunchCooperativeKernel((const void*)lstm_coop, dim3(192), dim3(256), args,
                             SMEM_BYTES, stream);

  head_kernel<<<256, 256, 0, stream>>>(hb, wpred, bpred, out);
}